// Round 1
// baseline (630.184 us; speedup 1.0000x reference)
//
#include <hip/hip_runtime.h>
#include <math.h>

// AttentionBlock3D: b=1, C=256, n=4096, 8 heads x 32 dim, GROUPS=8, EPS=1e-5
// Pipeline:
//  K1 gn_stats:   per-group mean/rstd (8 groups x 131072 elems)
//  K2 fold:       w2 = w_qkv * alpha[c], bias0[o] = sum_c w_qkv*beta[c]
//                 (groupnorm folded into QKV weights -> xn never materialized)
//  K3 gemm_qkv:   qkv(768x4096) = w2 @ x + bias0          (fp32 tiled)
//  K4 attn:       flash attention per head -> outT(4096x256)
//  K5 gemm_out:   y(256x4096) = w_out @ outT^T + b_out     (fp32 tiled)

#define LOG2E 1.4426950408889634f

// ---------------- K1: group stats ----------------
__global__ __launch_bounds__(256) void gn_stats_kernel(const float* __restrict__ x,
                                                       float* __restrict__ stats) {
  int g = blockIdx.x;
  const float4* p = reinterpret_cast<const float4*>(x + (size_t)g * 131072);
  float s = 0.f, q = 0.f;
  for (int i = threadIdx.x; i < 32768; i += 256) {
    float4 v = p[i];
    s += (v.x + v.y) + (v.z + v.w);
    q += (v.x * v.x + v.y * v.y) + (v.z * v.z + v.w * v.w);
  }
  for (int off = 32; off > 0; off >>= 1) {
    s += __shfl_down(s, off);
    q += __shfl_down(q, off);
  }
  __shared__ float ss[4], sq[4];
  int w = threadIdx.x >> 6, lane = threadIdx.x & 63;
  if (lane == 0) { ss[w] = s; sq[w] = q; }
  __syncthreads();
  if (threadIdx.x == 0) {
    float S = (ss[0] + ss[1]) + (ss[2] + ss[3]);
    float Q = (sq[0] + sq[1]) + (sq[2] + sq[3]);
    float mean = S * (1.f / 131072.f);
    float var = Q * (1.f / 131072.f) - mean * mean;
    stats[g * 2 + 0] = mean;
    stats[g * 2 + 1] = rsqrtf(var + 1e-5f);
  }
}

// ---------------- K2: fold groupnorm into qkv weights ----------------
__global__ __launch_bounds__(256) void fold_kernel(const float* __restrict__ w_qkv,
                                                   const float* __restrict__ gnw,
                                                   const float* __restrict__ gnb,
                                                   const float* __restrict__ stats,
                                                   float* __restrict__ w2,
                                                   float* __restrict__ bias0) {
  int wid = (blockIdx.x * 256 + threadIdx.x) >> 6;  // row 0..767
  int lane = threadIdx.x & 63;
  float part = 0.f;
#pragma unroll
  for (int cc = 0; cc < 4; ++cc) {
    int c = lane + cc * 64;
    int g = c >> 5;
    float mean = stats[2 * g], rstd = stats[2 * g + 1];
    float al = rstd * gnw[c];
    float be = gnb[c] - mean * al;
    float wv = w_qkv[wid * 256 + c];
    w2[wid * 256 + c] = wv * al;
    part += wv * be;
  }
  for (int off = 32; off > 0; off >>= 1) part += __shfl_down(part, off);
  if (lane == 0) bias0[wid] = part;
}

// ---------------- K3: qkv = w2(768x256) @ x(256x4096) + bias0 ----------------
#define FMA16(a, b, acc)                                                                 \
  acc[0][0] += a.x * b.x; acc[0][1] += a.x * b.y; acc[0][2] += a.x * b.z; acc[0][3] += a.x * b.w; \
  acc[1][0] += a.y * b.x; acc[1][1] += a.y * b.y; acc[1][2] += a.y * b.z; acc[1][3] += a.y * b.w; \
  acc[2][0] += a.z * b.x; acc[2][1] += a.z * b.y; acc[2][2] += a.z * b.z; acc[2][3] += a.z * b.w; \
  acc[3][0] += a.w * b.x; acc[3][1] += a.w * b.y; acc[3][2] += a.w * b.z; acc[3][3] += a.w * b.w;

__global__ __launch_bounds__(256) void gemm_qkv_kernel(const float* __restrict__ A,
                                                       const float* __restrict__ B,
                                                       const float* __restrict__ bias0,
                                                       float* __restrict__ C) {
  __shared__ float As[32][68];
  __shared__ float Bs[32][68];
  int m0 = blockIdx.y * 64, n0 = blockIdx.x * 64;
  int t = threadIdx.x;
  int tx = t & 15, ty = t >> 4;
  float acc[4][4] = {};
  for (int k0 = 0; k0 < 256; k0 += 32) {
    int ka = t & 31, ra = t >> 5;
#pragma unroll
    for (int it = 0; it < 8; ++it) {
      int row = ra + it * 8;
      As[ka][row] = A[(m0 + row) * 256 + k0 + ka];
    }
    int nb = t & 63, kb = t >> 6;
#pragma unroll
    for (int it = 0; it < 8; ++it) {
      int k = kb + it * 4;
      Bs[k][nb] = B[(size_t)(k0 + k) * 4096 + n0 + nb];
    }
    __syncthreads();
#pragma unroll
    for (int k = 0; k < 32; ++k) {
      float4 a = *(const float4*)&As[k][ty * 4];
      float4 b = *(const float4*)&Bs[k][tx * 4];
      FMA16(a, b, acc)
    }
    __syncthreads();
  }
#pragma unroll
  for (int i = 0; i < 4; ++i) {
    int o = m0 + ty * 4 + i;
    float bo = bias0[o];
    float4 r = make_float4(acc[i][0] + bo, acc[i][1] + bo, acc[i][2] + bo, acc[i][3] + bo);
    *(float4*)&C[(size_t)o * 4096 + n0 + tx * 4] = r;
  }
}

// ---------------- K4: flash attention ----------------
// grid 256 blocks x 256 threads. head = blockIdx.x & 7 (one head per XCD for L2
// locality), i-block = blockIdx.x >> 3 (128 queries). 4 waves split j in 1024-chunks,
// each wave keeps private online-softmax state; merged at the end via LDS.
__global__ __launch_bounds__(256) void attn_kernel(const float* __restrict__ qkv,
                                                   float* __restrict__ outT) {
  __shared__ float lds[9216];  // per-wave KVt [4][2][32][36]; reused for merge
  int h = blockIdx.x & 7;
  int i0 = (blockIdx.x >> 3) * 128;
  int t = threadIdx.x;
  int w = t >> 6, lane = t & 63;
  const float* Qg = qkv + (size_t)(h * 32) * 4096;
  const float* Kg = qkv + (size_t)(256 + h * 32) * 4096;
  const float* Vg = qkv + (size_t)(512 + h * 32) * 4096;

  // load 2 queries per lane into registers (coalesced per-d rows), pre-scaled
  float q1[32], q2[32];
#pragma unroll
  for (int d = 0; d < 32; ++d) {
    q1[d] = Qg[(size_t)d * 4096 + i0 + lane] * 0.17677669529663687f;
    q2[d] = Qg[(size_t)d * 4096 + i0 + 64 + lane] * 0.17677669529663687f;
  }

  float m1 = -1e30f, l1 = 0.f, m2 = -1e30f, l2 = 0.f;
  float acc1[32] = {}, acc2[32] = {};
  float* KVt = lds + w * 2304;  // [2][32][36]

#pragma unroll 1
  for (int jt = 0; jt < 32; ++jt) {
    int j0 = w * 1024 + jt * 32;
    // stage K,V tile transposed (wave-private slice; no barrier needed)
    {
      int jj = lane & 31, dh = lane >> 5;
#pragma unroll
      for (int d0 = 0; d0 < 16; ++d0) {
        int d = dh + d0 * 2;
        KVt[jj * 36 + d] = Kg[(size_t)d * 4096 + j0 + jj];
        KVt[1152 + jj * 36 + d] = Vg[(size_t)d * 4096 + j0 + jj];
      }
    }
#pragma unroll 2
    for (int jj = 0; jj < 32; ++jj) {
      const float* kk = &KVt[jj * 36];
      float s1a = 0, s1b = 0, s1c = 0, s1d = 0;
      float s2a = 0, s2b = 0, s2c = 0, s2d = 0;
#pragma unroll
      for (int d = 0; d < 32; d += 4) {
        float4 kv = *(const float4*)&kk[d];
        s1a += q1[d] * kv.x; s1b += q1[d + 1] * kv.y;
        s1c += q1[d + 2] * kv.z; s1d += q1[d + 3] * kv.w;
        s2a += q2[d] * kv.x; s2b += q2[d + 1] * kv.y;
        s2c += q2[d + 2] * kv.z; s2d += q2[d + 3] * kv.w;
      }
      float s1 = (s1a + s1b) + (s1c + s1d);
      float s2 = (s2a + s2b) + (s2c + s2d);

      float nm1 = fmaxf(m1, s1);
      float p1 = exp2f((s1 - nm1) * LOG2E);
      if (nm1 > m1) {
        float c1 = exp2f((m1 - nm1) * LOG2E);
        l1 *= c1; m1 = nm1;
#pragma unroll
        for (int d = 0; d < 32; ++d) acc1[d] *= c1;
      }
      l1 += p1;
      float nm2 = fmaxf(m2, s2);
      float p2 = exp2f((s2 - nm2) * LOG2E);
      if (nm2 > m2) {
        float c2 = exp2f((m2 - nm2) * LOG2E);
        l2 *= c2; m2 = nm2;
#pragma unroll
        for (int d = 0; d < 32; ++d) acc2[d] *= c2;
      }
      l2 += p2;
      const float* vv = &KVt[1152 + jj * 36];
#pragma unroll
      for (int d = 0; d < 32; d += 4) {
        float4 v4 = *(const float4*)&vv[d];
        acc1[d] += p1 * v4.x; acc1[d + 1] += p1 * v4.y;
        acc1[d + 2] += p1 * v4.z; acc1[d + 3] += p1 * v4.w;
        acc2[d] += p2 * v4.x; acc2[d + 1] += p2 * v4.y;
        acc2[d + 2] += p2 * v4.z; acc2[d + 3] += p2 * v4.w;
      }
    }
  }

  // ---- merge 4 waves' partial (m,l,acc) ----
  __syncthreads();
  float* mlbuf = lds;  // [4][128][2]
  mlbuf[(w * 128 + lane) * 2 + 0] = m1;
  mlbuf[(w * 128 + lane) * 2 + 1] = l1;
  mlbuf[(w * 128 + 64 + lane) * 2 + 0] = m2;
  mlbuf[(w * 128 + 64 + lane) * 2 + 1] = l2;
  __syncthreads();
  float M1 = -1e30f, M2 = -1e30f;
#pragma unroll
  for (int ww = 0; ww < 4; ++ww) {
    M1 = fmaxf(M1, mlbuf[(ww * 128 + lane) * 2]);
    M2 = fmaxf(M2, mlbuf[(ww * 128 + 64 + lane) * 2]);
  }
  float L1 = 0.f, L2 = 0.f;
#pragma unroll
  for (int ww = 0; ww < 4; ++ww) {
    L1 += mlbuf[(ww * 128 + lane) * 2 + 1] * exp2f((mlbuf[(ww * 128 + lane) * 2] - M1) * LOG2E);
    L2 += mlbuf[(ww * 128 + 64 + lane) * 2 + 1] * exp2f((mlbuf[(ww * 128 + 64 + lane) * 2] - M2) * LOG2E);
  }
  float sc1 = exp2f((m1 - M1) * LOG2E);
  float sc2 = exp2f((m2 - M2) * LOG2E);
#pragma unroll
  for (int d = 0; d < 32; ++d) { acc1[d] *= sc1; acc2[d] *= sc2; }
  float* invbuf = lds + 1024;  // [128]
  if (w == 0) { invbuf[lane] = 1.f / L1; invbuf[64 + lane] = 1.f / L2; }
  float* accbuf = lds + 1536;  // [4][128][9]
#pragma unroll
  for (int ch = 0; ch < 4; ++ch) {
    __syncthreads();
#pragma unroll
    for (int dd = 0; dd < 8; ++dd) {
      accbuf[(w * 128 + lane) * 9 + dd] = acc1[ch * 8 + dd];
      accbuf[(w * 128 + 64 + lane) * 9 + dd] = acc2[ch * 8 + dd];
    }
    __syncthreads();
    int q = t & 127, hf = t >> 7;
    float r[4];
#pragma unroll
    for (int dd = 0; dd < 4; ++dd) {
      int di = hf * 4 + dd;
      r[dd] = ((accbuf[q * 9 + di] + accbuf[(128 + q) * 9 + di]) +
               (accbuf[(256 + q) * 9 + di] + accbuf[(384 + q) * 9 + di])) * invbuf[q];
    }
    *(float4*)&outT[(size_t)(i0 + q) * 256 + h * 32 + ch * 8 + hf * 4] =
        make_float4(r[0], r[1], r[2], r[3]);
  }
}

// ---------------- K5: y = w_out(256x256) @ outT^T + b_out ----------------
__global__ __launch_bounds__(256) void gemm_out_kernel(const float* __restrict__ A,
                                                       const float* __restrict__ Bt,
                                                       const float* __restrict__ bias,
                                                       float* __restrict__ C) {
  __shared__ float As[32][68];
  __shared__ float Bs[32][68];
  int m0 = blockIdx.y * 64, n0 = blockIdx.x * 64;
  int t = threadIdx.x;
  int tx = t & 15, ty = t >> 4;
  float acc[4][4] = {};
  for (int k0 = 0; k0 < 256; k0 += 32) {
    int ka = t & 31, ra = t >> 5;
#pragma unroll
    for (int it = 0; it < 8; ++it) {
      int row = ra + it * 8;
      As[ka][row] = A[(m0 + row) * 256 + k0 + ka];
      Bs[ka][row] = Bt[(size_t)(n0 + row) * 256 + k0 + ka];
    }
    __syncthreads();
#pragma unroll
    for (int k = 0; k < 32; ++k) {
      float4 a = *(const float4*)&As[k][ty * 4];
      float4 b = *(const float4*)&Bs[k][tx * 4];
      FMA16(a, b, acc)
    }
    __syncthreads();
  }
#pragma unroll
  for (int i = 0; i < 4; ++i) {
    int o = m0 + ty * 4 + i;
    float bo = bias[o];
    float4 r = make_float4(acc[i][0] + bo, acc[i][1] + bo, acc[i][2] + bo, acc[i][3] + bo);
    *(float4*)&C[(size_t)o * 4096 + n0 + tx * 4] = r;
  }
}

extern "C" void kernel_launch(void* const* d_in, const int* in_sizes, int n_in,
                              void* d_out, int out_size, void* d_ws, size_t ws_size,
                              hipStream_t stream) {
  const float* x = (const float*)d_in[0];
  const float* gnw = (const float*)d_in[1];
  const float* gnb = (const float*)d_in[2];
  const float* w_qkv = (const float*)d_in[3];
  const float* w_out = (const float*)d_in[4];
  const float* b_out = (const float*)d_in[5];
  float* ws = (float*)d_ws;

  float* stats = ws;                    // 16
  float* bias0 = ws + 64;               // 768
  float* w2 = ws + 1024;                // 196608
  float* qkv = w2 + 196608;             // 3145728  (768 x 4096)
  float* attno = qkv + 3145728;         // 1048576  (outT: 4096 x 256)
  float* y = (float*)d_out;

  hipLaunchKernelGGL(gn_stats_kernel, dim3(8), dim3(256), 0, stream, x, stats);
  hipLaunchKernelGGL(fold_kernel, dim3(192), dim3(256), 0, stream, w_qkv, gnw, gnb, stats, w2, bias0);
  hipLaunchKernelGGL(gemm_qkv_kernel, dim3(64, 12), dim3(256), 0, stream, w2, x, bias0, qkv);
  hipLaunchKernelGGL(attn_kernel, dim3(256), dim3(256), 0, stream, qkv, attno);
  hipLaunchKernelGGL(gemm_out_kernel, dim3(64, 4), dim3(256), 0, stream, w_out, attno, b_out, y);
}

// Round 2
// 121.052 us; speedup vs baseline: 5.2059x; 5.2059x over previous
//
#include <hip/hip_runtime.h>
#include <hip/hip_bf16.h>
#include <math.h>

// AttentionBlock3D: b=1, C=256, n=4096, 8 heads x 32 dim, GROUPS=8, EPS=1e-5
//  K1 gn_stats:  per-group mean/rstd
//  K2 fold:      groupnorm folded into QKV weights (w2, bias0)
//  K3 gemm_qkv:  fp32 tiled GEMM, writes bf16 Qt[h][pos][32] (pre-scaled),
//                Kt[h][pos][32], Vd[h][32][pos]
//  K4 attn_mfma: flash attention, mfma_16x16x32 (QK^T swapped) +
//                mfma_16x16x16 (PV), barrier-free main loop, LDS wave-merge
//  K5 gemm_out:  fp32 tiled GEMM y = w_out @ outT^T + b_out

#define LOG2E 1.4426950408889634f

typedef __attribute__((ext_vector_type(8))) short bf16x8;
typedef __attribute__((ext_vector_type(4))) short bf16x4;
typedef __attribute__((ext_vector_type(4))) float f32x4;
typedef __attribute__((ext_vector_type(4))) unsigned short u16x4;

__device__ inline short f2bf(float f) {
  __hip_bfloat16 h = __float2bfloat16(f);
  return *reinterpret_cast<short*>(&h);
}

// ---------------- K1: group stats ----------------
__global__ __launch_bounds__(256) void gn_stats_kernel(const float* __restrict__ x,
                                                       float* __restrict__ stats) {
  int g = blockIdx.x;
  const float4* p = reinterpret_cast<const float4*>(x + (size_t)g * 131072);
  float s = 0.f, q = 0.f;
  for (int i = threadIdx.x; i < 32768; i += 256) {
    float4 v = p[i];
    s += (v.x + v.y) + (v.z + v.w);
    q += (v.x * v.x + v.y * v.y) + (v.z * v.z + v.w * v.w);
  }
  for (int off = 32; off > 0; off >>= 1) {
    s += __shfl_down(s, off);
    q += __shfl_down(q, off);
  }
  __shared__ float ss[4], sq[4];
  int w = threadIdx.x >> 6, lane = threadIdx.x & 63;
  if (lane == 0) { ss[w] = s; sq[w] = q; }
  __syncthreads();
  if (threadIdx.x == 0) {
    float S = (ss[0] + ss[1]) + (ss[2] + ss[3]);
    float Q = (sq[0] + sq[1]) + (sq[2] + sq[3]);
    float mean = S * (1.f / 131072.f);
    float var = Q * (1.f / 131072.f) - mean * mean;
    stats[g * 2 + 0] = mean;
    stats[g * 2 + 1] = rsqrtf(var + 1e-5f);
  }
}

// ---------------- K2: fold groupnorm into qkv weights ----------------
__global__ __launch_bounds__(256) void fold_kernel(const float* __restrict__ w_qkv,
                                                   const float* __restrict__ gnw,
                                                   const float* __restrict__ gnb,
                                                   const float* __restrict__ stats,
                                                   float* __restrict__ w2,
                                                   float* __restrict__ bias0) {
  int wid = (blockIdx.x * 256 + threadIdx.x) >> 6;  // row 0..767
  int lane = threadIdx.x & 63;
  float part = 0.f;
#pragma unroll
  for (int cc = 0; cc < 4; ++cc) {
    int c = lane + cc * 64;
    int g = c >> 5;
    float mean = stats[2 * g], rstd = stats[2 * g + 1];
    float al = rstd * gnw[c];
    float be = gnb[c] - mean * al;
    float wv = w_qkv[wid * 256 + c];
    w2[wid * 256 + c] = wv * al;
    part += wv * be;
  }
  for (int off = 32; off > 0; off >>= 1) part += __shfl_down(part, off);
  if (lane == 0) bias0[wid] = part;
}

// ---------------- K3: qkv GEMM (fp32), bf16 layout stores ----------------
#define FMA16(a, b, acc)                                                                 \
  acc[0][0] += a.x * b.x; acc[0][1] += a.x * b.y; acc[0][2] += a.x * b.z; acc[0][3] += a.x * b.w; \
  acc[1][0] += a.y * b.x; acc[1][1] += a.y * b.y; acc[1][2] += a.y * b.z; acc[1][3] += a.y * b.w; \
  acc[2][0] += a.z * b.x; acc[2][1] += a.z * b.y; acc[2][2] += a.z * b.z; acc[2][3] += a.z * b.w; \
  acc[3][0] += a.w * b.x; acc[3][1] += a.w * b.y; acc[3][2] += a.w * b.z; acc[3][3] += a.w * b.w;

__global__ __launch_bounds__(256) void gemm_qkv_kernel(const float* __restrict__ A,
                                                       const float* __restrict__ B,
                                                       const float* __restrict__ bias0,
                                                       unsigned short* __restrict__ qt,
                                                       unsigned short* __restrict__ ktb,
                                                       unsigned short* __restrict__ vdb) {
  __shared__ float As[32][68];
  __shared__ float Bs[32][68];
  int m0 = blockIdx.y * 64, n0 = blockIdx.x * 64;
  int t = threadIdx.x;
  int tx = t & 15, ty = t >> 4;
  float acc[4][4] = {};
  for (int k0 = 0; k0 < 256; k0 += 32) {
    int ka = t & 31, ra = t >> 5;
#pragma unroll
    for (int it = 0; it < 8; ++it) {
      int row = ra + it * 8;
      As[ka][row] = A[(m0 + row) * 256 + k0 + ka];
    }
    int nb = t & 63, kb = t >> 6;
#pragma unroll
    for (int it = 0; it < 8; ++it) {
      int k = kb + it * 4;
      Bs[k][nb] = B[(size_t)(k0 + k) * 4096 + n0 + nb];
    }
    __syncthreads();
#pragma unroll
    for (int k = 0; k < 32; ++k) {
      float4 a = *(const float4*)&As[k][ty * 4];
      float4 b = *(const float4*)&Bs[k][tx * 4];
      FMA16(a, b, acc)
    }
    __syncthreads();
  }
  // epilogue: bias + route to bf16 layouts
  int o0 = m0 + ty * 4;              // 4 consecutive output rows
  int t3 = o0 >> 8;                  // 0=q, 1=k, 2=v
  int h = (o0 >> 5) & 7;
  int d0 = o0 & 31;
  int pos0 = n0 + tx * 4;
  float bo[4];
#pragma unroll
  for (int i = 0; i < 4; ++i) bo[i] = bias0[o0 + i];
  if (t3 == 0) {
#pragma unroll
    for (int j = 0; j < 4; ++j) {
      u16x4 v;
#pragma unroll
      for (int i = 0; i < 4; ++i)
        v[i] = (unsigned short)f2bf((acc[i][j] + bo[i]) * 0.17677669529663687f);
      *(u16x4*)(qt + (size_t)(h * 4096 + pos0 + j) * 32 + d0) = v;
    }
  } else if (t3 == 1) {
#pragma unroll
    for (int j = 0; j < 4; ++j) {
      u16x4 v;
#pragma unroll
      for (int i = 0; i < 4; ++i)
        v[i] = (unsigned short)f2bf(acc[i][j] + bo[i]);
      *(u16x4*)(ktb + (size_t)(h * 4096 + pos0 + j) * 32 + d0) = v;
    }
  } else {
#pragma unroll
    for (int i = 0; i < 4; ++i) {
      u16x4 v;
#pragma unroll
      for (int j = 0; j < 4; ++j)
        v[j] = (unsigned short)f2bf(acc[i][j] + bo[i]);
      *(u16x4*)(vdb + (size_t)(h * 32 + d0 + i) * 4096 + pos0) = v;
    }
  }
}

// ---------------- K4: MFMA flash attention ----------------
// 512 blocks: h = b&7 (XCD affinity), i0 = (b>>3)*64. 4 waves split j-range
// (1024 j each), barrier-free main loop, all state in registers.
// QK^T swapped: St = mfma_16x16x32(A=K-tile, B=Q-tile) -> lane(c,g) holds
// S^T[j=js*16+g*4+r][i=c]. These P values are exactly the B-frag of
// mfma_16x16x16 for PV (k = g*4+e) -> no transpose anywhere.
__global__ __launch_bounds__(256) void attn_mfma_kernel(const unsigned short* __restrict__ qt,
                                                        const unsigned short* __restrict__ ktb,
                                                        const unsigned short* __restrict__ vdb,
                                                        float* __restrict__ outT) {
  const int b = blockIdx.x;
  const int h = b & 7;
  const int i0 = (b >> 3) * 64;
  const int t = threadIdx.x;
  const int w = t >> 6;
  const int lane = t & 63;
  const int c = lane & 15;
  const int g = lane >> 4;
  const f32x4 zero4 = {0.f, 0.f, 0.f, 0.f};

  // Q fragments (4 i-tiles of 16 queries), loaded once
  const unsigned short* qb = qt + (size_t)h * 131072 + (size_t)(i0 + c) * 32 + g * 8;
  bf16x8 qf[4];
#pragma unroll
  for (int it = 0; it < 4; ++it) qf[it] = *(const bf16x8*)(qb + it * 512);

  const unsigned short* kp = ktb + (size_t)h * 131072 + (size_t)(w * 1024 + c) * 32 + g * 8;
  const unsigned short* vp = vdb + (size_t)(h * 32 + c) * 4096 + w * 1024 + g * 4;

  float m[4] = {-1e30f, -1e30f, -1e30f, -1e30f};
  float l[4] = {0.f, 0.f, 0.f, 0.f};
  f32x4 oacc[4][2];
#pragma unroll
  for (int it = 0; it < 4; ++it) {
    oacc[it][0] = zero4;
    oacc[it][1] = zero4;
  }

  for (int jt = 0; jt < 16; ++jt) {
    bf16x8 kf[4];
#pragma unroll
    for (int js = 0; js < 4; ++js)
      kf[js] = *(const bf16x8*)(kp + jt * 2048 + js * 512);
    bf16x4 vf[2][4];
#pragma unroll
    for (int dh = 0; dh < 2; ++dh)
#pragma unroll
      for (int js = 0; js < 4; ++js)
        vf[dh][js] = *(const bf16x4*)(vp + dh * 65536 + jt * 64 + js * 16);

#pragma unroll
    for (int it = 0; it < 4; ++it) {
      f32x4 st[4];
#pragma unroll
      for (int js = 0; js < 4; ++js)
        st[js] = __builtin_amdgcn_mfma_f32_16x16x32_bf16(kf[js], qf[it], zero4, 0, 0, 0);
      // tile max for this lane's 16 scores, then unify across the 4
      // lanes sharing query column c (lanes c, c+16, c+32, c+48)
      float pm = fmaxf(fmaxf(fmaxf(st[0][0], st[0][1]), fmaxf(st[0][2], st[0][3])),
                       fmaxf(fmaxf(st[1][0], st[1][1]), fmaxf(st[1][2], st[1][3])));
      float pm2 = fmaxf(fmaxf(fmaxf(st[2][0], st[2][1]), fmaxf(st[2][2], st[2][3])),
                        fmaxf(fmaxf(st[3][0], st[3][1]), fmaxf(st[3][2], st[3][3])));
      pm = fmaxf(pm, pm2);
      pm = fmaxf(pm, __shfl_xor(pm, 16));
      pm = fmaxf(pm, __shfl_xor(pm, 32));
      float nm = fmaxf(m[it], pm);
      float f = __builtin_amdgcn_exp2f((m[it] - nm) * LOG2E);
      m[it] = nm;
      l[it] *= f;
      oacc[it][0] *= f;
      oacc[it][1] *= f;
      float lsum = 0.f;
      bf16x4 pb[4];
#pragma unroll
      for (int js = 0; js < 4; ++js) {
#pragma unroll
        for (int r = 0; r < 4; ++r) {
          float p = __builtin_amdgcn_exp2f((st[js][r] - nm) * LOG2E);
          lsum += p;
          pb[js][r] = f2bf(p);
        }
      }
      l[it] += lsum;
#pragma unroll
      for (int js = 0; js < 4; ++js) {
        oacc[it][0] = __builtin_amdgcn_mfma_f32_16x16x16bf16_1k(vf[0][js], pb[js], oacc[it][0], 0, 0, 0);
        oacc[it][1] = __builtin_amdgcn_mfma_f32_16x16x16bf16_1k(vf[1][js], pb[js], oacc[it][1], 0, 0, 0);
      }
    }
  }

  // ---- merge the 4 waves' partial (m, l, oacc) via LDS ----
  __shared__ float lds_o[4][4][2][4][4][17];  // [w][it][dh][g][r][c] padded
  __shared__ float lds_m[4][4][16];
  __shared__ float lds_l[4][4][16];
#pragma unroll
  for (int it = 0; it < 4; ++it) {
    float lv = l[it];
    lv += __shfl_xor(lv, 16);
    lv += __shfl_xor(lv, 32);
    if (g == 0) {
      lds_m[w][it][c] = m[it];
      lds_l[w][it][c] = lv;
    }
#pragma unroll
    for (int dh = 0; dh < 2; ++dh)
#pragma unroll
      for (int r = 0; r < 4; ++r)
        lds_o[w][it][dh][g][r][c] = oacc[it][dh][r];
  }
  __syncthreads();
  {
    const int it = w;  // each wave merges one i-tile
    float mv[4], fw[4];
    float M = -1e30f;
#pragma unroll
    for (int ww = 0; ww < 4; ++ww) {
      mv[ww] = lds_m[ww][it][c];
      M = fmaxf(M, mv[ww]);
    }
    float L = 0.f;
#pragma unroll
    for (int ww = 0; ww < 4; ++ww) {
      fw[ww] = __builtin_amdgcn_exp2f((mv[ww] - M) * LOG2E);
      L += lds_l[ww][it][c] * fw[ww];
    }
    float inv = 1.f / L;
#pragma unroll
    for (int dh = 0; dh < 2; ++dh) {
      float4 o;
      float* op = &o.x;
#pragma unroll
      for (int r = 0; r < 4; ++r) {
        float v = 0.f;
#pragma unroll
        for (int ww = 0; ww < 4; ++ww) v += lds_o[ww][it][dh][g][r][c] * fw[ww];
        op[r] = v * inv;
      }
      *(float4*)&outT[(size_t)(i0 + it * 16 + c) * 256 + h * 32 + dh * 16 + g * 4] = o;
    }
  }
}

// ---------------- K5: y = w_out(256x256) @ outT^T + b_out ----------------
__global__ __launch_bounds__(256) void gemm_out_kernel(const float* __restrict__ A,
                                                       const float* __restrict__ Bt,
                                                       const float* __restrict__ bias,
                                                       float* __restrict__ C) {
  __shared__ float As[32][68];
  __shared__ float Bs[32][68];
  int m0 = blockIdx.y * 64, n0 = blockIdx.x * 64;
  int t = threadIdx.x;
  int tx = t & 15, ty = t >> 4;
  float acc[4][4] = {};
  for (int k0 = 0; k0 < 256; k0 += 32) {
    int ka = t & 31, ra = t >> 5;
#pragma unroll
    for (int it = 0; it < 8; ++it) {
      int row = ra + it * 8;
      As[ka][row] = A[(m0 + row) * 256 + k0 + ka];
      Bs[ka][row] = Bt[(size_t)(n0 + row) * 256 + k0 + ka];
    }
    __syncthreads();
#pragma unroll
    for (int k = 0; k < 32; ++k) {
      float4 a = *(const float4*)&As[k][ty * 4];
      float4 b = *(const float4*)&Bs[k][tx * 4];
      FMA16(a, b, acc)
    }
    __syncthreads();
  }
#pragma unroll
  for (int i = 0; i < 4; ++i) {
    int o = m0 + ty * 4 + i;
    float bo = bias[o];
    float4 r = make_float4(acc[i][0] + bo, acc[i][1] + bo, acc[i][2] + bo, acc[i][3] + bo);
    *(float4*)&C[(size_t)o * 4096 + n0 + tx * 4] = r;
  }
}

extern "C" void kernel_launch(void* const* d_in, const int* in_sizes, int n_in,
                              void* d_out, int out_size, void* d_ws, size_t ws_size,
                              hipStream_t stream) {
  const float* x = (const float*)d_in[0];
  const float* gnw = (const float*)d_in[1];
  const float* gnb = (const float*)d_in[2];
  const float* w_qkv = (const float*)d_in[3];
  const float* w_out = (const float*)d_in[4];
  const float* b_out = (const float*)d_in[5];
  float* ws = (float*)d_ws;

  float* stats = ws;                          // 16 floats
  float* bias0 = ws + 64;                     // 768
  float* w2 = ws + 1024;                      // 196608
  unsigned short* qt = (unsigned short*)(ws + 197632);   // 8*4096*32 bf16 = 2MB
  unsigned short* ktb = qt + 1048576;                    // 2MB
  unsigned short* vdb = ktb + 1048576;                   // 2MB
  float* attno = (float*)(vdb + 1048576);                // outT 4096x256 f32 = 4MB
  float* y = (float*)d_out;

  hipLaunchKernelGGL(gn_stats_kernel, dim3(8), dim3(256), 0, stream, x, stats);
  hipLaunchKernelGGL(fold_kernel, dim3(192), dim3(256), 0, stream, w_qkv, gnw, gnb, stats, w2, bias0);
  hipLaunchKernelGGL(gemm_qkv_kernel, dim3(64, 12), dim3(256), 0, stream, w2, x, bias0, qt, ktb, vdb);
  hipLaunchKernelGGL(attn_mfma_kernel, dim3(512), dim3(256), 0, stream, qt, ktb, vdb, attno);
  hipLaunchKernelGGL(gemm_out_kernel, dim3(64, 4), dim3(256), 0, stream, w_out, attno, b_out, y);
}